// Round 1
// baseline (757.309 us; speedup 1.0000x reference)
//
#include <hip/hip_runtime.h>

namespace {
constexpr int GS = 128;
constexpr int NPTS = GS * GS;          // 16384 points per grid
constexpr float RES = 0.25f;
constexpr int NGRIDS = 16;
constexpr int BLOCK = 256;
constexpr int CHUNKS = NPTS / BLOCK;   // 64 chunks of query points per (grid,dir)
}

__global__ void zero_kernel(float* out) { *out = 0.0f; }

// One block: (grid g, direction dir, chunk of 256 query points).
// Database grid staged in LDS (64 KB); brute-force min over all 16384 points.
__global__ __launch_bounds__(BLOCK) void chamfer_kernel(
    const float* __restrict__ pred, const float* __restrict__ gt,
    float* __restrict__ out)
{
    __shared__ float zb[NPTS];

    const int bid = blockIdx.x;
    const int chunk = bid & (CHUNKS - 1);
    const int pair = bid >> 6;          // 0..31
    const int g = pair >> 1;
    const int dir = pair & 1;
    // dir 0: queries = gt, database = pred   (dist1 in reference)
    // dir 1: queries = pred, database = gt   (dist2)
    const float* __restrict__ A = (dir == 0) ? gt + g * NPTS : pred + g * NPTS;
    const float* __restrict__ B = (dir == 0) ? pred + g * NPTS : gt + g * NPTS;

    const int tid = threadIdx.x;
    {   // stage database grid into LDS, vectorized
        const float4* src = reinterpret_cast<const float4*>(B);
        float4* dst = reinterpret_cast<float4*>(zb);
        for (int k = tid; k < NPTS / 4; k += BLOCK) dst[k] = src[k];
    }
    __syncthreads();

    const int i = chunk * BLOCK + tid;          // query point index
    const float xi = (float)(i >> 7) * RES;     // row * RES
    const float yi = (float)(i & (GS - 1)) * RES;
    const float za = A[i];

    // 4 independent min accumulators to break the v_min_f32 dep chain
    float m0 = 1e30f, m1 = 1e30f, m2 = 1e30f, m3 = 1e30f;
    for (int r = 0; r < GS; ++r) {
        const float dx = xi - (float)r * RES;
        const float dx2 = dx * dx;
        const float4* row = reinterpret_cast<const float4*>(zb + r * GS);
        #pragma unroll 8
        for (int c4 = 0; c4 < GS / 4; ++c4) {
            const float4 z4 = row[c4];          // broadcast: all lanes same addr
            const float dy0 = yi - (float)(4 * c4) * RES;
            const float dy1 = dy0 - RES;
            const float dy2 = dy0 - 2.0f * RES;
            const float dy3 = dy0 - 3.0f * RES;
            const float dz0 = za - z4.x;
            const float dz1 = za - z4.y;
            const float dz2 = za - z4.z;
            const float dz3 = za - z4.w;
            const float d0 = fmaf(dz0, dz0, fmaf(dy0, dy0, dx2));
            const float d1 = fmaf(dz1, dz1, fmaf(dy1, dy1, dx2));
            const float d2 = fmaf(dz2, dz2, fmaf(dy2, dy2, dx2));
            const float d3 = fmaf(dz3, dz3, fmaf(dy3, dy3, dx2));
            m0 = fminf(m0, d0);
            m1 = fminf(m1, d1);
            m2 = fminf(m2, d2);
            m3 = fminf(m3, d3);
        }
    }
    float best = fminf(fminf(m0, m1), fminf(m2, m3));

    // block sum-reduction of the per-query minima
    for (int off = 32; off > 0; off >>= 1) best += __shfl_down(best, off);
    __shared__ float wsum[BLOCK / 64];
    const int wave = tid >> 6;
    if ((tid & 63) == 0) wsum[wave] = best;
    __syncthreads();
    if (tid == 0) {
        float s = 0.0f;
        for (int w = 0; w < BLOCK / 64; ++w) s += wsum[w];
        atomicAdd(out, s * (1.0f / NGRIDS));   // mean over grids
    }
}

extern "C" void kernel_launch(void* const* d_in, const int* in_sizes, int n_in,
                              void* d_out, int out_size, void* d_ws, size_t ws_size,
                              hipStream_t stream) {
    const float* pred = (const float*)d_in[0];  // inputs (1,1,512,512)
    const float* gt   = (const float*)d_in[1];  // targets (1,512,512)
    float* out = (float*)d_out;
    zero_kernel<<<1, 1, 0, stream>>>(out);
    chamfer_kernel<<<NGRIDS * 2 * CHUNKS, BLOCK, 0, stream>>>(pred, gt, out);
}

// Round 2
// 47.231 us; speedup vs baseline: 16.0342x; 16.0342x over previous
//
#include <hip/hip_runtime.h>

namespace {
constexpr int GS = 128;
constexpr int NPTS = GS * GS;          // 16384 points per grid
constexpr float RES = 0.25f;
constexpr float RES2 = RES * RES;      // 0.0625
constexpr int NGRIDS = 16;
constexpr int BLOCK = 512;
constexpr int CHUNKS = NPTS / BLOCK;   // 32 chunks of query points per (grid,dir)
constexpr int PAD = 3;                 // phase-A window radius
constexpr int PW = GS + 2 * PAD;       // 134 padded width
constexpr float PADV = 1.0e18f;        // pad value: (za-PADV)^2 ~ 1e36, finite, never wins
}

__global__ void zero_kernel(float* out) { *out = 0.0f; }

// One block: (grid g, direction dir, chunk of 512 query points).
// Database grid staged in LDS with a PAD-wide border of huge values so the
// 7x7 phase-A scan needs no clamping and its planar term folds to a constant.
// Exact min: phase A covers Chebyshev radii 0..3; expanding-ring phase B runs
// (rarely, wave-predicated) while B > (k*RES)^2 — cells at radius >= k have
// planar distance >= k*RES, so on exit B is the true minimum.
__global__ __launch_bounds__(BLOCK) void chamfer_kernel(
    const float* __restrict__ pred, const float* __restrict__ gt,
    float* __restrict__ out)
{
    __shared__ float zb[PW * PW];      // 71824 B -> 2 blocks/CU

    const int bid = blockIdx.x;
    const int chunk = bid & (CHUNKS - 1);
    const int pair = bid >> 5;          // CHUNKS=32
    const int g = pair >> 1;
    const int dir = pair & 1;
    const float* __restrict__ A = (dir == 0) ? gt + g * NPTS : pred + g * NPTS;
    const float* __restrict__ B_ = (dir == 0) ? pred + g * NPTS : gt + g * NPTS;

    const int tid = threadIdx.x;

    // ---- stage: fill whole padded buffer with PADV, then interior ----
    {
        float4* dst4 = reinterpret_cast<float4*>(zb);
        const float4 pv = make_float4(PADV, PADV, PADV, PADV);
        constexpr int NP4 = (PW * PW) / 4;   // 17956/4 = 4489 exact
        for (int k = tid; k < NP4; k += BLOCK) dst4[k] = pv;
    }
    __syncthreads();
    {
        const float4* src = reinterpret_cast<const float4*>(B_);
        for (int k = tid; k < NPTS / 4; k += BLOCK) {
            const float4 v = src[k];
            const int r = (4 * k) >> 7;
            const int c = (4 * k) & (GS - 1);       // 4 elems never cross a row
            float* p = &zb[(r + PAD) * PW + c + PAD];
            p[0] = v.x; p[1] = v.y; p[2] = v.z; p[3] = v.w;
        }
    }
    __syncthreads();

    const int i = chunk * BLOCK + tid;  // query point index
    const int ri = i >> 7;
    const int ci = i & (GS - 1);
    const float za = A[i];

    // ---- phase A: 7x7 window, no clamping (pad), planar term is constant ----
    float bacc[4] = {1e30f, 1e30f, 1e30f, 1e30f};   // break the v_min dep chain
    const float* q = &zb[(ri + PAD) * PW + ci + PAD];
    #pragma unroll
    for (int dr = -PAD; dr <= PAD; ++dr) {
        #pragma unroll
        for (int dc = -PAD; dc <= PAD; ++dc) {
            const float z = q[dr * PW + dc];
            const float dz = za - z;
            const float c2 = (float)(dr * dr + dc * dc) * RES2;  // compile-time
            const int t = (dr + PAD) * 7 + (dc + PAD);
            bacc[t & 3] = fminf(bacc[t & 3], fmaf(dz, dz, c2));
        }
    }
    float best = fminf(fminf(bacc[0], bacc[1]), fminf(bacc[2], bacc[3]));

    // ---- phase B: expanding rings, wave-predicated, clamped at borders ----
    int k = PAD + 1;
    while (true) {
        const float bound = ((float)k * RES) * ((float)k * RES);
        const bool done = (best <= bound) || (k >= GS);
        if (__all(done)) break;
        if (!done) {
            for (int dr = -k; dr <= k; ++dr) {
                const int rr = min(max(ri + dr, 0), GS - 1);
                const float dx = (float)(ri - rr) * RES;
                const float dx2 = dx * dx;
                const float* row = &zb[(rr + PAD) * PW + PAD];
                const int clo = min(max(ci - k, 0), GS - 1);
                const int chi = min(max(ci + k, 0), GS - 1);
                if (dr == -k || dr == k) {
                    for (int cc = clo; cc <= chi; ++cc) {
                        const float dy = (float)(ci - cc) * RES;
                        const float dz = za - row[cc];
                        best = fminf(best, fmaf(dz, dz, fmaf(dy, dy, dx2)));
                    }
                } else {
                    {
                        const float dy = (float)(ci - clo) * RES;
                        const float dz = za - row[clo];
                        best = fminf(best, fmaf(dz, dz, fmaf(dy, dy, dx2)));
                    }
                    {
                        const float dy = (float)(ci - chi) * RES;
                        const float dz = za - row[chi];
                        best = fminf(best, fmaf(dz, dz, fmaf(dy, dy, dx2)));
                    }
                }
            }
        }
        ++k;
    }

    // ---- block sum-reduction of per-query minima ----
    for (int off = 32; off > 0; off >>= 1) best += __shfl_down(best, off);
    __shared__ float wsum[BLOCK / 64];
    const int wave = tid >> 6;
    if ((tid & 63) == 0) wsum[wave] = best;
    __syncthreads();
    if (tid == 0) {
        float s = 0.0f;
        #pragma unroll
        for (int w = 0; w < BLOCK / 64; ++w) s += wsum[w];
        atomicAdd(out, s * (1.0f / NGRIDS));
    }
}

extern "C" void kernel_launch(void* const* d_in, const int* in_sizes, int n_in,
                              void* d_out, int out_size, void* d_ws, size_t ws_size,
                              hipStream_t stream) {
    const float* pred = (const float*)d_in[0];  // inputs (1,1,512,512)
    const float* gt   = (const float*)d_in[1];  // targets (1,512,512)
    float* out = (float*)d_out;
    zero_kernel<<<1, 1, 0, stream>>>(out);
    chamfer_kernel<<<NGRIDS * 2 * CHUNKS, BLOCK, 0, stream>>>(pred, gt, out);
}

// Round 3
// 41.780 us; speedup vs baseline: 18.1263x; 1.1305x over previous
//
#include <hip/hip_runtime.h>

namespace {
constexpr int GS = 128;
constexpr int NPTS = GS * GS;          // 16384 points per grid
constexpr float RES = 0.25f;
constexpr float RES2 = RES * RES;
constexpr int NGRIDS = 16;
constexpr int BLOCK = 256;
constexpr int CHUNKS = NPTS / BLOCK;   // 64 chunks per (grid,dir)
constexpr int NBLOCKS = NGRIDS * 2 * CHUNKS;  // 2048
}

// One thread per query point. 7x7 clamped window read directly from
// global (L1-resident: each block's window is ~4KB). Exact min:
// phase A covers all in-grid cells at Chebyshev radius <= 3 with true
// distances; phase B (rare, wave-predicated) expands rings while
// best > (k*RES)^2 — cells at radius >= k have planar dist >= k*RES.
__global__ __launch_bounds__(BLOCK) void chamfer_kernel(
    const float* __restrict__ pred, const float* __restrict__ gt,
    float* __restrict__ partial)
{
    const int bid = blockIdx.x;
    const int chunk = bid & (CHUNKS - 1);
    const int pair = bid >> 6;
    const int g = pair >> 1;
    const int dir = pair & 1;
    const float* __restrict__ A  = (dir == 0) ? gt + g * NPTS : pred + g * NPTS;
    const float* __restrict__ DB = (dir == 0) ? pred + g * NPTS : gt + g * NPTS;

    const int tid = threadIdx.x;
    const int i = chunk * BLOCK + tid;
    const int ri = i >> 7;
    const int ci = i & (GS - 1);
    const float za = A[i];

    // clamped row/col indices and their true planar terms
    int rr[7]; float dx2[7]; int cc[7]; float dy2[7];
    #pragma unroll
    for (int t = 0; t < 7; ++t) {
        int r = min(max(ri + t - 3, 0), GS - 1);
        rr[t] = r;
        const float dx = (float)(ri - r) * RES;
        dx2[t] = dx * dx;
        int c = min(max(ci + t - 3, 0), GS - 1);
        cc[t] = c;
        const float dy = (float)(ci - c) * RES;
        dy2[t] = dy * dy;
    }

    // phase A: 49 independent loads (coalesced per wave), 4 min accumulators
    float bacc[4] = {1e30f, 1e30f, 1e30f, 1e30f};
    #pragma unroll
    for (int a = 0; a < 7; ++a) {
        const float* __restrict__ row = DB + rr[a] * GS;
        #pragma unroll
        for (int b = 0; b < 7; ++b) {
            const float z = row[cc[b]];
            const float dz = za - z;
            const int t = a * 7 + b;
            bacc[t & 3] = fminf(bacc[t & 3], fmaf(dz, dz, dx2[a] + dy2[b]));
        }
    }
    float best = fminf(fminf(bacc[0], bacc[1]), fminf(bacc[2], bacc[3]));

    // phase B: expanding rings from global, wave-predicated, clamped
    int k = 4;
    while (true) {
        float bound = (float)k * RES;
        bound *= bound;
        const bool done = (best <= bound) || (k >= GS);
        if (__all(done)) break;
        if (!done) {
            const int clo = min(max(ci - k, 0), GS - 1);
            const int chi = min(max(ci + k, 0), GS - 1);
            for (int dr = -k; dr <= k; ++dr) {
                const int r = min(max(ri + dr, 0), GS - 1);
                const float dx = (float)(ri - r) * RES;
                const float dxx2 = dx * dx;
                const float* __restrict__ row = DB + r * GS;
                if (dr == -k || dr == k) {
                    for (int c = clo; c <= chi; ++c) {
                        const float dy = (float)(ci - c) * RES;
                        const float dz = za - row[c];
                        best = fminf(best, fmaf(dz, dz, fmaf(dy, dy, dxx2)));
                    }
                } else {
                    {
                        const float dy = (float)(ci - clo) * RES;
                        const float dz = za - row[clo];
                        best = fminf(best, fmaf(dz, dz, fmaf(dy, dy, dxx2)));
                    }
                    {
                        const float dy = (float)(ci - chi) * RES;
                        const float dz = za - row[chi];
                        best = fminf(best, fmaf(dz, dz, fmaf(dy, dy, dxx2)));
                    }
                }
            }
        }
        ++k;
    }

    // block sum-reduction -> one partial per block (no atomics)
    for (int off = 32; off > 0; off >>= 1) best += __shfl_down(best, off);
    __shared__ float wsum[BLOCK / 64];
    if ((tid & 63) == 0) wsum[tid >> 6] = best;
    __syncthreads();
    if (tid == 0) {
        float s = 0.0f;
        #pragma unroll
        for (int w = 0; w < BLOCK / 64; ++w) s += wsum[w];
        partial[bid] = s;
    }
}

__global__ __launch_bounds__(1024) void reduce_kernel(
    const float* __restrict__ partial, float* __restrict__ out)
{
    const int tid = threadIdx.x;
    float s = partial[tid] + partial[tid + 1024];   // NBLOCKS = 2048
    for (int off = 32; off > 0; off >>= 1) s += __shfl_down(s, off);
    __shared__ float wsum[16];
    if ((tid & 63) == 0) wsum[tid >> 6] = s;
    __syncthreads();
    if (tid == 0) {
        float t = 0.0f;
        #pragma unroll
        for (int w = 0; w < 16; ++w) t += wsum[w];
        *out = t * (1.0f / NGRIDS);
    }
}

extern "C" void kernel_launch(void* const* d_in, const int* in_sizes, int n_in,
                              void* d_out, int out_size, void* d_ws, size_t ws_size,
                              hipStream_t stream) {
    const float* pred = (const float*)d_in[0];  // inputs (1,1,512,512)
    const float* gt   = (const float*)d_in[1];  // targets (1,512,512)
    float* partial = (float*)d_ws;              // 2048 floats
    float* out = (float*)d_out;
    chamfer_kernel<<<NBLOCKS, BLOCK, 0, stream>>>(pred, gt, partial);
    reduce_kernel<<<1, 1024, 0, stream>>>(partial, out);
}

// Round 4
// 17.234 us; speedup vs baseline: 43.9433x; 2.4243x over previous
//
#include <hip/hip_runtime.h>

namespace {
constexpr int GS = 128;
constexpr int NPTS = GS * GS;          // 16384 points per grid
constexpr float RES = 0.25f;
constexpr int NGRIDS = 16;
constexpr int BLOCK = 256;
constexpr int CHUNKS = NPTS / BLOCK;   // 64 chunks per (grid,dir)
constexpr int NBLOCKS = NGRIDS * 2 * CHUNKS;  // 2048
}

// One thread per query point. Phase A: 7x7 clamped window read directly from
// global (L1-resident). A thread is exact-done if best <= (4*RES)^2 = 1.0
// (all cells at Chebyshev radius >= 4 have planar dist >= 1.0).
// Phase B: wave-COOPERATIVE. Stragglers (rare, |za| tail) are broadcast one
// at a time; all 64 lanes scan the (2K+1)^2 square with K = ceil(4*sqrt(bestA))
// in 8x8 tiles, then min-reduce. One pass is exact: cells at radius >= K have
// planar >= (K*RES)^2 >= bestA >= final best.
__global__ __launch_bounds__(BLOCK) void chamfer_kernel(
    const float* __restrict__ pred, const float* __restrict__ gt,
    float* __restrict__ partial)
{
    const int bid = blockIdx.x;
    const int chunk = bid & (CHUNKS - 1);
    const int pair = bid >> 6;
    const int g = pair >> 1;
    const int dir = pair & 1;
    const float* __restrict__ A  = (dir == 0) ? gt + g * NPTS : pred + g * NPTS;
    const float* __restrict__ DB = (dir == 0) ? pred + g * NPTS : gt + g * NPTS;

    const int tid = threadIdx.x;
    const int i = chunk * BLOCK + tid;
    const int ri = i >> 7;
    const int ci = i & (GS - 1);
    const float za = A[i];

    // clamped row/col indices and true planar terms
    int rr[7]; float dx2[7]; int cc[7]; float dy2[7];
    #pragma unroll
    for (int t = 0; t < 7; ++t) {
        int r = min(max(ri + t - 3, 0), GS - 1);
        rr[t] = r;
        const float dx = (float)(ri - r) * RES;
        dx2[t] = dx * dx;
        int c = min(max(ci + t - 3, 0), GS - 1);
        cc[t] = c;
        const float dy = (float)(ci - c) * RES;
        dy2[t] = dy * dy;
    }

    // phase A: 49 independent loads (coalesced per wave), 4 min accumulators
    float bacc[4] = {1e30f, 1e30f, 1e30f, 1e30f};
    #pragma unroll
    for (int a = 0; a < 7; ++a) {
        const float* __restrict__ row = DB + rr[a] * GS;
        #pragma unroll
        for (int b = 0; b < 7; ++b) {
            const float z = row[cc[b]];
            const float dz = za - z;
            const int t = a * 7 + b;
            bacc[t & 3] = fminf(bacc[t & 3], fmaf(dz, dz, dx2[a] + dy2[b]));
        }
    }
    float best = fminf(fminf(bacc[0], bacc[1]), fminf(bacc[2], bacc[3]));

    // phase B: wave-cooperative scan for the rare stragglers
    const int lane = tid & 63;
    const int lr = lane >> 3, lc = lane & 7;   // 8x8 lane tile
    unsigned long long pend = __ballot(best > 1.0f);
    while (pend) {
        const int src = __ffsll(pend) - 1;
        pend &= pend - 1;
        const int qri = __shfl(ri, src);
        const int qci = __shfl(ci, src);
        const float qza = __shfl(za, src);
        const float qb  = __shfl(best, src);
        int K = (int)(4.0f * sqrtf(qb)) + 1;   // >= ceil(4*sqrt(qb))
        K = min(K, GS - 1);                    // radius 127 covers whole grid
        float m = 1e30f;
        for (int tr = -K; tr <= K; tr += 8) {
            const int dr = tr + lr;
            if (dr > K) continue;
            const int r = min(max(qri + dr, 0), GS - 1);
            const float dx = (float)(qri - r) * RES;
            const float dxx2 = dx * dx;
            const float* __restrict__ row = DB + r * GS;
            for (int tc = -K; tc <= K; tc += 8) {
                const int dc = tc + lc;
                if (dc > K) continue;
                const int c = min(max(qci + dc, 0), GS - 1);
                const float dy = (float)(qci - c) * RES;
                const float dz = qza - row[c];
                m = fminf(m, fmaf(dz, dz, fmaf(dy, dy, dxx2)));
            }
        }
        #pragma unroll
        for (int off = 32; off > 0; off >>= 1) m = fminf(m, __shfl_xor(m, off));
        if (lane == src) best = fminf(best, m);
    }

    // block sum-reduction -> one partial per block (no atomics)
    for (int off = 32; off > 0; off >>= 1) best += __shfl_down(best, off);
    __shared__ float wsum[BLOCK / 64];
    if ((tid & 63) == 0) wsum[tid >> 6] = best;
    __syncthreads();
    if (tid == 0) {
        float s = 0.0f;
        #pragma unroll
        for (int w = 0; w < BLOCK / 64; ++w) s += wsum[w];
        partial[bid] = s;
    }
}

__global__ __launch_bounds__(1024) void reduce_kernel(
    const float* __restrict__ partial, float* __restrict__ out)
{
    const int tid = threadIdx.x;
    float s = partial[tid] + partial[tid + 1024];   // NBLOCKS = 2048
    for (int off = 32; off > 0; off >>= 1) s += __shfl_down(s, off);
    __shared__ float wsum[16];
    if ((tid & 63) == 0) wsum[tid >> 6] = s;
    __syncthreads();
    if (tid == 0) {
        float t = 0.0f;
        #pragma unroll
        for (int w = 0; w < 16; ++w) t += wsum[w];
        *out = t * (1.0f / NGRIDS);
    }
}

extern "C" void kernel_launch(void* const* d_in, const int* in_sizes, int n_in,
                              void* d_out, int out_size, void* d_ws, size_t ws_size,
                              hipStream_t stream) {
    const float* pred = (const float*)d_in[0];  // inputs (1,1,512,512)
    const float* gt   = (const float*)d_in[1];  // targets (1,512,512)
    float* partial = (float*)d_ws;              // 2048 floats
    float* out = (float*)d_out;
    chamfer_kernel<<<NBLOCKS, BLOCK, 0, stream>>>(pred, gt, partial);
    reduce_kernel<<<1, 1024, 0, stream>>>(partial, out);
}